// Round 3
// baseline (14.691 us; speedup 1.0000x reference)
//
#include <hip/hip_runtime.h>

// Problem constants from the reference (fixed problem instance).
#define BB 32      // batch
#define KK 8       // channels
#define HH 512     // height
#define WW 512     // width
#define SS 50      // sample count
#define HID 64     // hidden dim
#define CTX 71     // 9*K - 1

// One 64-thread block (one wave) per (b, s) pair.
// Lane h owns hidden unit h. W1 column h lives in registers (prefetched,
// latency-overlapped with the z gather). 72 gathered values staged in LDS.
__global__ void __launch_bounds__(64)
le_core_kernel(const float* __restrict__ z,
               const float* __restrict__ W1,
               const float* __restrict__ b1,
               const float* __restrict__ W2,
               const float* __restrict__ b2,
               const int*   __restrict__ b_idx,
               const int*   __restrict__ i_idx,
               const int*   __restrict__ j_idx,
               float*       __restrict__ ws)
{
    const int bs = blockIdx.x;          // 0 .. BB*SS-1
    const int b  = bs / SS;
    const int s  = bs - b * SS;
    const int h  = threadIdx.x;         // 0 .. 63

    __shared__ float full[9 * KK];      // 72 gathered values

    // Block-uniform sample indices (compiler emits scalar loads).
    const int i0   = i_idx[s];
    const int j0   = j_idx[s];
    const int bsel = b_idx[s];
    const int rm   = 4 * KK + bsel;     // removed (center) position

    // Issue the z gather (the long-latency HBM chain) ASAP.
    // p = n*K + k, n in [0,9), k in [0,8). Lane h covers p=h; lanes 0..7
    // additionally cover p=64+h (the n=8 / (+1,+1) neighbor row).
    {
        const int n  = h >> 3;
        const int k  = h & 7;
        const int ni = (i0 + (n / 3) - 1) & (HH - 1);   // torus wrap
        const int nj = (j0 + (n % 3) - 1) & (WW - 1);
        full[h] = z[(((b * KK + k) * HH + ni) * WW) + nj];
    }
    if (h < 8) {
        // p = 64 + h  ->  n = 8 (di=+1, dj=+1), k = h
        const int ni = (i0 + 1) & (HH - 1);
        const int nj = (j0 + 1) & (WW - 1);
        full[64 + h] = z[(((b * KK + h) * HH + ni) * WW) + nj];
    }

    // Prefetch all weights for hidden unit h into registers; these loads are
    // independent of the gather and fly concurrently with it.
    float w[CTX];
    #pragma unroll
    for (int t = 0; t < CTX; ++t) w[t] = W1[t * HID + h];
    const float bias1 = b1[h];
    const float w2h   = W2[h];

    __syncthreads();

    // Pure LDS-broadcast + register FMA loop (no memory latency left).
    float acc = bias1;
    #pragma unroll
    for (int t = 0; t < CTX; ++t) {
        const int src = t + (t >= rm ? 1 : 0);  // skip removed element
        acc = fmaf(full[src], w[t], acc);
    }
    const float hv      = acc > 0.0f ? acc : 0.0f;     // relu
    float       contrib = hv * w2h;

    // Wave-64 reduction of the output dot product.
    #pragma unroll
    for (int off = 32; off > 0; off >>= 1)
        contrib += __shfl_down(contrib, off);

    if (h == 0) {
        const float logit  = contrib + b2[0];
        const float pred   = logit > 0.0f ? 1.0f : 0.0f;
        const float actual = full[rm];                  // z[b, b_idx, i, j]
        ws[bs] = (pred != actual) ? 1.0f : 0.0f;
    }
}

// Single-wave reduction of the 1600 per-pair error flags -> mean.
__global__ void __launch_bounds__(64)
le_reduce_kernel(const float* __restrict__ ws, float* __restrict__ out)
{
    const int tid = threadIdx.x;        // 0..63
    float s = 0.0f;
    #pragma unroll
    for (int i = tid; i < BB * SS; i += 64) s += ws[i];  // 25 coalesced loads

    #pragma unroll
    for (int off = 32; off > 0; off >>= 1)
        s += __shfl_down(s, off);

    if (tid == 0) out[0] = s * (1.0f / (float)(BB * SS));
}

extern "C" void kernel_launch(void* const* d_in, const int* in_sizes, int n_in,
                              void* d_out, int out_size, void* d_ws, size_t ws_size,
                              hipStream_t stream)
{
    const float* z     = (const float*)d_in[0];
    const float* W1    = (const float*)d_in[1];
    const float* b1    = (const float*)d_in[2];
    const float* W2    = (const float*)d_in[3];
    const float* b2    = (const float*)d_in[4];
    const int*   b_idx = (const int*)d_in[5];
    const int*   i_idx = (const int*)d_in[6];
    const int*   j_idx = (const int*)d_in[7];

    float* out = (float*)d_out;
    float* ws  = (float*)d_ws;   // BB*SS floats = 6.4 KB scratch

    le_core_kernel<<<BB * SS, 64, 0, stream>>>(z, W1, b1, W2, b2,
                                               b_idx, i_idx, j_idx, ws);
    le_reduce_kernel<<<1, 64, 0, stream>>>(ws, out);
}